// Round 5
// baseline (1024.631 us; speedup 1.0000x reference)
//
#include <hip/hip_runtime.h>
#include <math.h>

typedef unsigned short u16;
typedef unsigned int   u32;
typedef __attribute__((ext_vector_type(8))) short short8;
typedef __attribute__((ext_vector_type(4))) float f32x4;

typedef const void __attribute__((address_space(1))) gvoid_t;
typedef void       __attribute__((address_space(3))) svoid_t;

__device__ __forceinline__ void gload_lds16(const void* g, void* l){
    __builtin_amdgcn_global_load_lds((gvoid_t*)g, (svoid_t*)l, 16, 0, 0);
}

__device__ __forceinline__ float gelu_f(float x){
    return 0.5f * x * (1.0f + erff(x * 0.70710678118654752f));
}
__device__ __forceinline__ u16 f2b(float x){
    union{float f; u32 u;} v; v.f = x;
    u32 r = (v.u + 0x7fffu + ((v.u >> 16) & 1u)) >> 16;
    return (u16)r;
}
__device__ __forceinline__ float b2f(u16 h){
    union{u32 u; float f;} v; v.u = ((u32)h) << 16; return v.f;
}

// ===================== bf16 MFMA GEMM =====================
// A: bf16 [M][lda] row-major (k contiguous). B: bf16 [N][ldb] row-major (k contiguous).
// Tile 128x128, BK=32, 256 threads = 4 waves, each wave 64x64 (4x4 frags of 16x16).
// Staging via global_load_lds dwordx4: LDS layout [kb][128][8] is linear in c=kb*128+m.
// EPI: 0:+bias->bf16  1:+bias,GELU->bf16  2:+bias->f32  3:/(rowv[r]+1e-8)->bf16
//      4:+bias+resid->f32  5:exp(acc-rowv[r])*scale->f32  6:exp(acc-rowv[r])*scale->bf16
//      8: plain f32 store into per-splitK slice (C += bz*sC)
template<int EPI, int GUARD, int CGUARD>
__global__ __launch_bounds__(256)
void gemm_bf16(const u16* __restrict__ A, int lda,
               const u16* __restrict__ B, int ldb,
               void* __restrict__ Cv, int ldc,
               const float* __restrict__ bias,
               const float* __restrict__ rowv,
               const float* __restrict__ resid,
               int Mrows, int Ncols, int K, int splitK,
               long sA, long sB, long sC, long sRV,
               float scale)
{
    const int bz = blockIdx.z;
    const int b  = bz / splitK, kc = bz % splitK;
    A += (long)b * sA;  B += (long)b * sB;
    const float* rv = (EPI == 3 || EPI == 5 || EPI == 6) ? rowv + (long)b * sRV : nullptr;

    __shared__ u16 As[4096];   // [kb][m][8] == linear c*8 u16, c = kb*128+m
    __shared__ u16 Bs[4096];

    const int tid = threadIdx.x;
    const int row0 = blockIdx.y * 128, col0 = blockIdx.x * 128;

    f32x4 acc[4][4] = {};

    const int l  = tid & 63, w = tid >> 6;
    const int wr = w >> 1,  wc = w & 1;
    const int g  = l >> 4,  mr = l & 15;

    const int kLen   = K / splitK;
    const int kStart = kc * kLen;

    const u16* gA[2]; const u16* gB[2];
    u16* lA[2]; u16* lB[2];
    #pragma unroll
    for (int q = 0; q < 2; q++){
        const int c = q * 256 + tid;
        const int m = c & 127, kb = c >> 7;
        gA[q] = A + (long)(row0 + m) * lda + kStart + kb * 8;
        gB[q] = B + (long)(col0 + m) * ldb + kStart + kb * 8;
        const int wbase = q * 256 + (tid & 192);   // wave-uniform chunk base
        lA[q] = As + wbase * 8;
        lB[q] = Bs + wbase * 8;
    }

    for (int k0 = 0; k0 < kLen; k0 += 32){
        __syncthreads();                       // prev iter's ds_reads done
        #pragma unroll
        for (int q = 0; q < 2; q++){
            gload_lds16(gA[q] + k0, lA[q]);
            gload_lds16(gB[q] + k0, lB[q]);
        }
        __syncthreads();                       // vmcnt(0) drained before barrier

        short8 af[4], bfr[4];
        #pragma unroll
        for (int i = 0; i < 4; i++)
            af[i] = *(const short8*)&As[(g * 128 + wr * 64 + i * 16 + mr) * 8];
        #pragma unroll
        for (int j = 0; j < 4; j++)
            bfr[j] = *(const short8*)&Bs[(g * 128 + wc * 64 + j * 16 + mr) * 8];
        #pragma unroll
        for (int i = 0; i < 4; i++)
            #pragma unroll
            for (int j = 0; j < 4; j++)
                acc[i][j] = __builtin_amdgcn_mfma_f32_16x16x32_bf16(af[i], bfr[j], acc[i][j], 0, 0, 0);
    }

    float* Cf = (float*)Cv + (EPI == 8 ? (long)bz : (long)b) * sC;
    u16*   Cb = (u16*)Cv   + (long)b * sC;

    #pragma unroll
    for (int i = 0; i < 4; i++){
        #pragma unroll
        for (int j = 0; j < 4; j++){
            const int col = col0 + wc * 64 + j * 16 + mr;
            if (CGUARD && col >= Ncols) continue;
            float bv = 0.f;
            if (EPI == 0 || EPI == 1 || EPI == 2 || EPI == 4) bv = bias[col];
            #pragma unroll
            for (int r = 0; r < 4; r++){
                const int row = row0 + wr * 64 + i * 16 + g * 4 + r;
                if (GUARD && row >= Mrows) continue;
                float vv = acc[i][j][r];
                if      (EPI == 1){ vv += bv; vv = gelu_f(vv); }
                else if (EPI == 3){ vv = vv / (rv[row] + 1e-8f); }
                else if (EPI == 4){ vv += bv + resid[(long)row * ldc + col]; }
                else if (EPI == 5 || EPI == 6){ vv = expf(vv - rv[row]) * scale; }
                else if (EPI == 8){ }
                else              { vv += bv; }
                if (EPI == 2 || EPI == 4 || EPI == 5 || EPI == 8) Cf[(long)row * ldc + col] = vv;
                else                                               Cb[(long)row * ldc + col] = f2b(vv);
            }
        }
    }
}

// tiled transpose: in f32 [R][C] -> out bf16 [C][R]; grid (C/64, R/64), 256 thr
__global__ __launch_bounds__(256)
void tr_kernel(const float* __restrict__ in, u16* __restrict__ out, long R, int C)
{
    __shared__ float t[64][65];
    const long cb = (long)blockIdx.x * 64, rb = (long)blockIdx.y * 64;
    const int tl = threadIdx.x & 63, tw = threadIdx.x >> 6;
    #pragma unroll
    for (int i = 0; i < 16; i++){
        const int r = tw + i * 4;
        t[r][tl] = in[(rb + r) * C + cb + tl];
    }
    __syncthreads();
    #pragma unroll
    for (int i = 0; i < 16; i++){
        const int c = tw + i * 4;
        out[(cb + c) * R + rb + tl] = f2b(t[tl][c]);
    }
}

// kptvb[b][i] = bf16( sum_{kc<7} kptv_all[b*7+kc][i] )
__global__ __launch_bounds__(256)
void kred_kernel(const float* __restrict__ in, u16* __restrict__ out, long n)
{
    long idx = (long)blockIdx.x * 256 + threadIdx.x;
    if (idx >= n) return;
    const long b = idx / 73728, r = idx - b * 73728;
    const float* s = in + b * 7 * 73728L + r;
    float acc = 0.f;
    #pragma unroll
    for (int kc = 0; kc < 7; kc++) acc += s[kc * 73728L];
    out[idx] = f2b(acc);
}

// LayerNorm over D=384 (f32 in); optional f32 and bf16 outputs.
__global__ __launch_bounds__(256)
void ln_kernel(const float* __restrict__ x, float* __restrict__ of, u16* __restrict__ ob,
               const float* __restrict__ g, const float* __restrict__ bta)
{
    const int lane = threadIdx.x & 63;
    const long r = (long)blockIdx.x * 4 + (threadIdx.x >> 6);
    const float* xr = x + r * 384;
    float v[6]; float s = 0.f;
    #pragma unroll
    for (int i = 0; i < 6; i++){ v[i] = xr[lane + i*64]; s += v[i]; }
    #pragma unroll
    for (int off = 32; off; off >>= 1) s += __shfl_xor(s, off);
    const float mu = s * (1.0f/384.0f);
    float q = 0.f;
    #pragma unroll
    for (int i = 0; i < 6; i++){ float d = v[i] - mu; q += d*d; }
    #pragma unroll
    for (int off = 32; off; off >>= 1) q += __shfl_xor(q, off);
    const float inv = rsqrtf(q * (1.0f/384.0f) + 1e-5f);
    #pragma unroll
    for (int i = 0; i < 6; i++){
        const int c = lane + i*64;
        const float val = (v[i] - mu) * inv * g[c] + bta[c];
        if (of) of[r * 384 + c] = val;
        if (ob) ob[r * 384 + c] = f2b(val);
    }
}

// xd[r] = 0.5*||x_row||^2 over 384 bf16 cols
__global__ __launch_bounds__(256)
void xd_b_kernel(const u16* __restrict__ x, float* __restrict__ xd)
{
    const int lane = threadIdx.x & 63;
    const long r = (long)blockIdx.x * 4 + (threadIdx.x >> 6);
    const u16* xr = x + r * 384;
    float s = 0.f;
    #pragma unroll
    for (int i = 0; i < 6; i++){ float a = b2f(xr[lane + i*64]); s += a*a; }
    #pragma unroll
    for (int off = 32; off; off >>= 1) s += __shfl_xor(s, off);
    if (lane == 0) xd[r] = 0.5f * s;
}

// Dn[r] = dot(qp_bf16[r,:192], kpsum[r/T,:192])
__global__ __launch_bounds__(256)
void dn_kernel(const u16* __restrict__ qp, const float* __restrict__ kpsum,
               float* __restrict__ Dn, int T)
{
    const int lane = threadIdx.x & 63;
    const long r = (long)blockIdx.x * 4 + (threadIdx.x >> 6);
    const int b = (int)(r / T);
    const u16* qr = qp + r * 192;
    const float* ks = kpsum + (long)b * 192;
    float s = 0.f;
    #pragma unroll
    for (int i = 0; i < 3; i++){ const int m = lane + i*64; s += b2f(qr[m]) * ks[m]; }
    #pragma unroll
    for (int off = 32; off; off >>= 1) s += __shfl_xor(s, off);
    if (lane == 0) Dn[r] = s;
}

__global__ __launch_bounds__(192)
void kpsum_kernel(const float* __restrict__ kp, float* __restrict__ kpsum)
{
    const int b = blockIdx.x, ch = blockIdx.y, m = threadIdx.x;
    const float* base = kp + ((long)b * 3136 + (long)ch * 448) * 192 + m;
    float s = 0.f;
    for (int t = 0; t < 448; t++) s += base[(long)t * 192];
    atomicAdd(&kpsum[b * 192 + m], s);
}

__global__ __launch_bounds__(256)
void zero_kernel(float* __restrict__ p, long n)
{
    long i = (long)blockIdx.x * 256 + threadIdx.x;
    long stride = (long)gridDim.x * 256;
    for (; i < n; i += stride) p[i] = 0.f;
}

// concat(in1,in2) row-major -> bf16 [Mc][768]
__global__ __launch_bounds__(256)
void ca_kernel(const float* __restrict__ i1, const float* __restrict__ i2,
               u16* __restrict__ a0, long nquad)
{
    long idx = (long)blockIdx.x * 256 + threadIdx.x;
    if (idx >= nquad) return;
    const long r = idx / 192;
    const int  c0 = (int)(idx % 192) * 4;
    const float* src = (c0 < 384) ? &i1[r * 384 + c0] : &i2[r * 384 + (c0 - 384)];
    float4 v = *(const float4*)src;
    u32 w0 = (u32)f2b(v.x) | ((u32)f2b(v.y) << 16);
    u32 w1 = (u32)f2b(v.z) | ((u32)f2b(v.w) << 16);
    *(uint2*)&a0[r * 768 + c0] = make_uint2(w0, w1);
}

// wt[n*K + k] = bf16(w[k*N + n])
__global__ __launch_bounds__(256)
void wt_kernel(const float* __restrict__ w, u16* __restrict__ wt, int K, int N, long total)
{
    long idx = (long)blockIdx.x * 256 + threadIdx.x;
    if (idx >= total) return;
    const long n = idx / K, k = idx - n * K;
    wt[idx] = f2b(w[k * N + n]);
}

// flat f32 -> bf16
__global__ __launch_bounds__(256)
void cvt_kernel(const float* __restrict__ s, u16* __restrict__ d, long n4)
{
    long idx = (long)blockIdx.x * 256 + threadIdx.x;
    if (idx >= n4) return;
    float4 v = *(const float4*)&s[idx * 4];
    u32 w0 = (u32)f2b(v.x) | ((u32)f2b(v.y) << 16);
    u32 w1 = (u32)f2b(v.z) | ((u32)f2b(v.w) << 16);
    *(uint2*)&d[idx * 4] = make_uint2(w0, w1);
}

extern "C" void kernel_launch(void* const* d_in, const int* in_sizes, int n_in,
                              void* d_out, int out_size, void* d_ws, size_t ws_size,
                              hipStream_t stream)
{
    const long T = 3136;
    const float prm_scale = 0.07216878364870322f;  // 1/sqrt(192)

    const float* in1    = (const float*)d_in[0];
    const float* in2    = (const float*)d_in[1];
    const float* W1     = (const float*)d_in[2];
    const float* b1     = (const float*)d_in[3];
    const float* W2     = (const float*)d_in[4];
    const float* b2     = (const float*)d_in[5];
    const float* kqv_w  = (const float*)d_in[6];
    const float* kqv_b  = (const float*)d_in[7];
    const float* proj_w = (const float*)d_in[8];
    const float* proj_b = (const float*)d_in[9];
    const float* ln1_g  = (const float*)d_in[10];
    const float* ln1_b  = (const float*)d_in[11];
    const float* ln2_g  = (const float*)d_in[12];
    const float* ln2_b  = (const float*)d_in[13];
    const float* mlp_w1 = (const float*)d_in[14];
    const float* mlp_b1 = (const float*)d_in[15];
    const float* mlp_w2 = (const float*)d_in[16];
    const float* mlp_b2 = (const float*)d_in[17];
    const float* w_prm  = (const float*)d_in[18];
    float* out = (float*)d_out;

    // ---- workspace layout ----
    char* p = (char*)d_ws;
    auto alloc = [&](long bytes)->char*{ char* r = p; p += (bytes + 255) & ~255L; return r; };

    // chunk-invariant bf16 weights
    u16* w1t   = (u16*)alloc(294912L * 2);   // [384][768]
    u16* w2t   = (u16*)alloc(147456L * 2);   // [384][384]
    u16* kqvt  = (u16*)alloc(442368L * 2);   // [1152][384]
    u16* prjt  = (u16*)alloc(147456L * 2);
    u16* m1t   = (u16*)alloc(147456L * 2);
    u16* m2t   = (u16*)alloc(147456L * 2);
    u16* wprmb = (u16*)alloc(256L * 384 * 2); // [256 pad][384], rows 192+ zeroed
    char* chunkBase = p;

    // per-batch ws bytes:
    // bf16: a0 768 + h1b 384 + xnb 384 + qpb 192 + kqb 384 + vT 384 + kpT 256 = 2752*T*2
    // f32 : xf 384 + vf 384 + kp 192 + xdv 1 + Dn 1 = 962*T*4
    // f32 : kpsum 192 + kptv_all 7*73728 ; bf16: kptvb 73728
    const long perBatch = 2752L * T * 2 + 962L * T * 4
                        + (192L + 7L * 73728L) * 4 + 73728L * 2;
    const long fixed = (long)(chunkBase - (char*)d_ws) + (1L << 20);
    int nb = 2;
    for (int cand = 16; cand >= 2; cand >>= 1){
        if (fixed + (long)cand * perBatch + 128L * 1024 <= (long)ws_size){ nb = cand; break; }
    }

    const dim3 blk(256);

    // weight transpose/convert (idempotent per call)
    wt_kernel<<<dim3((294912 + 255) / 256), blk, 0, stream>>>(W1, w1t, 768, 384, 294912);
    wt_kernel<<<dim3((147456 + 255) / 256), blk, 0, stream>>>(W2, w2t, 384, 384, 147456);
    wt_kernel<<<dim3((442368 + 255) / 256), blk, 0, stream>>>(kqv_w, kqvt, 384, 1152, 442368);
    wt_kernel<<<dim3((147456 + 255) / 256), blk, 0, stream>>>(proj_w, prjt, 384, 384, 147456);
    wt_kernel<<<dim3((147456 + 255) / 256), blk, 0, stream>>>(mlp_w1, m1t, 384, 384, 147456);
    wt_kernel<<<dim3((147456 + 255) / 256), blk, 0, stream>>>(mlp_w2, m2t, 384, 384, 147456);
    zero_kernel<<<dim3(64), blk, 0, stream>>>((float*)wprmb, 256L * 384 / 2);
    cvt_kernel<<<dim3((18432 + 255) / 256), blk, 0, stream>>>(w_prm, wprmb, 18432);

    for (int b0 = 0; b0 < 16; b0 += nb){
        const long Mc = (long)nb * T;
        const int  gy128 = (int)(Mc / 128);
        const float* i1 = in1 + (long)b0 * T * 384;
        const float* i2 = in2 + (long)b0 * T * 384;
        float* outc = out + (long)b0 * T * 384;

        p = chunkBase;
        u16*  a0    = (u16*)alloc(Mc * 768 * 2);   // concat bf16 ; later mlp hidden
        u16*  h1b   = (u16*)alloc(Mc * 384 * 2);   // h1 bf16 ; later t_att bf16
        u16*  xnb   = (u16*)alloc(Mc * 384 * 2);   // xn bf16 ; later z bf16
        u16*  qpb   = (u16*)alloc(Mc * 192 * 2);   // qp bf16 (followed by allocs: OOB-read pad)
        u16*  kqb   = (u16*)alloc(Mc * 384 * 2);   // k bf16, then q bf16
        u16*  vT    = (u16*)alloc(384L * Mc * 2);  // v transposed bf16 [384][Mc]
        u16*  kpT   = (u16*)alloc(256L * Mc * 2);  // kp transposed bf16 [256 pad][Mc]
        float* xf   = (float*)alloc(Mc * 384 * 4); // x f32
        float* vf   = (float*)alloc(Mc * 384 * 4); // v f32
        float* kp   = (float*)alloc(Mc * 192 * 4); // kp f32
        float* xdv  = (float*)alloc(Mc * 4);
        float* Dn   = (float*)alloc(Mc * 4);
        float* kpsum= (float*)alloc((long)nb * 192 * 4);
        float* kptvA= (float*)alloc((long)nb * 7 * 73728 * 4);  // split-K slices
        u16*  kptvb = (u16*)alloc((long)nb * 73728 * 2);
        (void)alloc(128L * 1024);                   // tail pad

        // 0) a0 = bf16(concat)
        {
            long nq = Mc * 192;
            ca_kernel<<<dim3((unsigned)((nq + 255) / 256)), blk, 0, stream>>>(i1, i2, a0, nq);
        }
        // 1) h1 = GELU(a0 @ W1t^T + b1)  [bf16]
        gemm_bf16<1,0,0><<<dim3(3, gy128, 1), blk, 0, stream>>>(
            a0, 768, w1t, 768, h1b, 384, b1, nullptr, nullptr,
            (int)Mc, 384, 768, 1, 0,0,0,0, 0.f);
        // 2) x = h1 @ W2t^T + b2  [f32]
        gemm_bf16<2,0,0><<<dim3(3, gy128, 1), blk, 0, stream>>>(
            h1b, 384, w2t, 384, xf, 384, b2, nullptr, nullptr,
            (int)Mc, 384, 384, 1, 0,0,0,0, 0.f);
        // 3) LN1 -> xn bf16
        ln_kernel<<<dim3((unsigned)(Mc / 4)), blk, 0, stream>>>(xf, nullptr, xnb, ln1_g, ln1_b);
        // 4) k = xn @ kqvt[0:384] + b  [bf16]
        gemm_bf16<0,0,0><<<dim3(3, gy128, 1), blk, 0, stream>>>(
            xnb, 384, kqvt, 384, kqb, 384, kqv_b, nullptr, nullptr,
            (int)Mc, 384, 384, 1, 0,0,0,0, 0.f);
        xd_b_kernel<<<dim3((unsigned)(Mc / 4)), blk, 0, stream>>>(kqb, xdv);
        // 5) kp = exp(k @ wprm^T - xd)*scale  [f32, N=192 col-guarded]
        gemm_bf16<5,0,1><<<dim3(2, gy128, 1), blk, 0, stream>>>(
            kqb, 384, wprmb, 384, kp, 192, nullptr, xdv, nullptr,
            (int)Mc, 192, 384, 1, 0,0,0,0, prm_scale);
        // 6) kpsum
        zero_kernel<<<dim3(2), blk, 0, stream>>>(kpsum, (long)nb * 192);
        kpsum_kernel<<<dim3(nb, 7, 1), dim3(192), 0, stream>>>(kp, kpsum);
        // 7) q (overwrites kqb; kp GEMM already consumed k)
        gemm_bf16<0,0,0><<<dim3(3, gy128, 1), blk, 0, stream>>>(
            xnb, 384, kqvt + 384L * 384, 384, kqb, 384, kqv_b + 384, nullptr, nullptr,
            (int)Mc, 384, 384, 1, 0,0,0,0, 0.f);
        xd_b_kernel<<<dim3((unsigned)(Mc / 4)), blk, 0, stream>>>(kqb, xdv);
        gemm_bf16<6,0,1><<<dim3(2, gy128, 1), blk, 0, stream>>>(
            kqb, 384, wprmb, 384, qpb, 192, nullptr, xdv, nullptr,
            (int)Mc, 192, 384, 1, 0,0,0,0, prm_scale);
        // 8) v = xn @ kqvt[768:] + b  [f32]
        gemm_bf16<2,0,0><<<dim3(3, gy128, 1), blk, 0, stream>>>(
            xnb, 384, kqvt + 768L * 384, 384, vf, 384, kqv_b + 768, nullptr, nullptr,
            (int)Mc, 384, 384, 1, 0,0,0,0, 0.f);
        // 9) transposes: vf -> vT [384][Mc], kp -> kpT [192(256)][Mc]
        tr_kernel<<<dim3(6, (unsigned)(Mc / 64)), blk, 0, stream>>>(vf, vT, Mc, 384);
        tr_kernel<<<dim3(3, (unsigned)(Mc / 64)), blk, 0, stream>>>(kp, kpT, Mc, 192);
        // 10) kptv MFMA: [384][192] = vT(slice b) @ kpT(slice b)^T, split-K=7 slices
        gemm_bf16<8,0,1><<<dim3(2, 3, nb * 7), blk, 0, stream>>>(
            vT, (int)Mc, kpT, (int)Mc, kptvA, 192, nullptr, nullptr, nullptr,
            384, 192, 3136, 7, 3136, 3136, 73728, 0, 0.f);
        kred_kernel<<<dim3((unsigned)((long)nb * 73728 / 256)), blk, 0, stream>>>(
            kptvA, kptvb, (long)nb * 73728);
        // 11) Dn
        dn_kernel<<<dim3((unsigned)(Mc / 4)), blk, 0, stream>>>(qpb, kpsum, Dn, (int)T);
        // 12) t_att = (qp @ kptv^T) / (Dn+1e-8)  [bf16, per-batch, row-guarded]
        gemm_bf16<3,1,0><<<dim3(3, 25, nb), blk, 0, stream>>>(
            qpb, 192, kptvb, 192, h1b, 384, nullptr, Dn, nullptr,
            (int)T, 384, 192, 1, T*192, 73728, T*384, T, 0.f);
        // 13) y = t_att @ proj + proj_b + v  -> outc (f32)
        gemm_bf16<4,0,0><<<dim3(3, gy128, 1), blk, 0, stream>>>(
            h1b, 384, prjt, 384, outc, 384, proj_b, nullptr, vf,
            (int)Mc, 384, 384, 1, 0,0,0,0, 0.f);
        // 14) LN2 -> z bf16
        ln_kernel<<<dim3((unsigned)(Mc / 4)), blk, 0, stream>>>(outc, nullptr, xnb, ln2_g, ln2_b);
        // 15) h = GELU(z @ mlp1 + b)  [bf16] -> a0 region
        gemm_bf16<1,0,0><<<dim3(3, gy128, 1), blk, 0, stream>>>(
            xnb, 384, m1t, 384, a0, 384, mlp_b1, nullptr, nullptr,
            (int)Mc, 384, 384, 1, 0,0,0,0, 0.f);
        // 16) out = h @ mlp2 + b + y  (in-place residual on outc)
        gemm_bf16<4,0,0><<<dim3(3, gy128, 1), blk, 0, stream>>>(
            a0, 384, m2t, 384, outc, 384, mlp_b2, nullptr, outc,
            (int)Mc, 384, 384, 1, 0,0,0,0, 0.f);
    }
}

// Round 6
// 1004.782 us; speedup vs baseline: 1.0198x; 1.0198x over previous
//
#include <hip/hip_runtime.h>
#include <math.h>

typedef unsigned short u16;
typedef unsigned int   u32;
typedef __attribute__((ext_vector_type(8))) short short8;
typedef __attribute__((ext_vector_type(4))) float f32x4;

typedef const void __attribute__((address_space(1))) gvoid_t;
typedef void       __attribute__((address_space(3))) svoid_t;

__device__ __forceinline__ void gload_lds16(const void* g, void* l){
    __builtin_amdgcn_global_load_lds((gvoid_t*)g, (svoid_t*)l, 16, 0, 0);
}

__device__ __forceinline__ float gelu_f(float x){
    return 0.5f * x * (1.0f + erff(x * 0.70710678118654752f));
}
__device__ __forceinline__ u16 f2b(float x){
    union{float f; u32 u;} v; v.f = x;
    u32 r = (v.u + 0x7fffu + ((v.u >> 16) & 1u)) >> 16;
    return (u16)r;
}
__device__ __forceinline__ float b2f(u16 h){
    union{u32 u; float f;} v; v.u = ((u32)h) << 16; return v.f;
}

// ===================== bf16 MFMA GEMM =====================
// A: bf16 [M][lda] row-major (k contiguous). B: bf16 [N][ldb] row-major (k contiguous).
// Tile 128x128, BK=32, 256 threads = 4 waves, each wave 64x64 (4x4 frags of 16x16).
// 2-phase double-buffered pipeline (T3-minimum): one barrier per K-step;
// STAGE(t+1 -> buf^1) issues BEFORE the MFMA block on buf, so global_load_lds
// latency hides under MFMA; the drain happens at the next barrier.
// EPI: 0:+bias->bf16  1:+bias,GELU->bf16  2:+bias->f32  3:/(rowv[r]+1e-8)->bf16
//      4:+bias+resid->f32  5:exp(acc-rowv[r])*scale->f32  6:exp(acc-rowv[r])*scale->bf16
//      8: plain f32 store into per-splitK slice (C += bz*sC)
template<int EPI, int GUARD, int CGUARD>
__global__ __launch_bounds__(256)
void gemm_bf16(const u16* __restrict__ A, int lda,
               const u16* __restrict__ B, int ldb,
               void* __restrict__ Cv, int ldc,
               const float* __restrict__ bias,
               const float* __restrict__ rowv,
               const float* __restrict__ resid,
               int Mrows, int Ncols, int K, int splitK,
               long sA, long sB, long sC, long sRV,
               float scale)
{
    const int bz = blockIdx.z;
    const int b  = bz / splitK, kc = bz % splitK;
    A += (long)b * sA;  B += (long)b * sB;
    const float* rv = (EPI == 3 || EPI == 5 || EPI == 6) ? rowv + (long)b * sRV : nullptr;

    __shared__ u16 As[2][4096];   // [buf][kb][m][8] == linear c*8, c = kb*128+m
    __shared__ u16 Bs[2][4096];

    const int tid = threadIdx.x;
    const int row0 = blockIdx.y * 128, col0 = blockIdx.x * 128;

    f32x4 acc[4][4] = {};

    const int l  = tid & 63, w = tid >> 6;
    const int wr = w >> 1,  wc = w & 1;
    const int g  = l >> 4,  mr = l & 15;

    const int kLen   = K / splitK;
    const int kStart = kc * kLen;

    const u16* gA[2]; const u16* gB[2];
    int lOff[2];
    #pragma unroll
    for (int q = 0; q < 2; q++){
        const int c = q * 256 + tid;
        const int m = c & 127, kb = c >> 7;
        gA[q] = A + (long)(row0 + m) * lda + kStart + kb * 8;
        gB[q] = B + (long)(col0 + m) * ldb + kStart + kb * 8;
        lOff[q] = (q * 256 + (tid & 192)) * 8;     // wave-uniform chunk base (u16 idx)
    }

    // prologue: stage tile 0 into buf 0
    #pragma unroll
    for (int q = 0; q < 2; q++){
        gload_lds16(gA[q], &As[0][lOff[q]]);
        gload_lds16(gB[q], &Bs[0][lOff[q]]);
    }

    int cur = 0;
    for (int k0 = 0; k0 < kLen; k0 += 32){
        __syncthreads();   // drains stage into buf[cur] (vmcnt0) + prev ds_reads (lgkm)
        if (k0 + 32 < kLen){
            #pragma unroll
            for (int q = 0; q < 2; q++){
                gload_lds16(gA[q] + k0 + 32, &As[cur ^ 1][lOff[q]]);
                gload_lds16(gB[q] + k0 + 32, &Bs[cur ^ 1][lOff[q]]);
            }
        }

        short8 af[4], bfr[4];
        #pragma unroll
        for (int i = 0; i < 4; i++)
            af[i] = *(const short8*)&As[cur][(g * 128 + wr * 64 + i * 16 + mr) * 8];
        #pragma unroll
        for (int j = 0; j < 4; j++)
            bfr[j] = *(const short8*)&Bs[cur][(g * 128 + wc * 64 + j * 16 + mr) * 8];
        #pragma unroll
        for (int i = 0; i < 4; i++)
            #pragma unroll
            for (int j = 0; j < 4; j++)
                acc[i][j] = __builtin_amdgcn_mfma_f32_16x16x32_bf16(af[i], bfr[j], acc[i][j], 0, 0, 0);
        cur ^= 1;
    }

    float* Cf = (float*)Cv + (EPI == 8 ? (long)bz : (long)b) * sC;
    u16*   Cb = (u16*)Cv   + (long)b * sC;

    #pragma unroll
    for (int i = 0; i < 4; i++){
        #pragma unroll
        for (int j = 0; j < 4; j++){
            const int col = col0 + wc * 64 + j * 16 + mr;
            if (CGUARD && col >= Ncols) continue;
            float bv = 0.f;
            if (EPI == 0 || EPI == 1 || EPI == 2 || EPI == 4) bv = bias[col];
            #pragma unroll
            for (int r = 0; r < 4; r++){
                const int row = row0 + wr * 64 + i * 16 + g * 4 + r;
                if (GUARD && row >= Mrows) continue;
                float vv = acc[i][j][r];
                if      (EPI == 1){ vv += bv; vv = gelu_f(vv); }
                else if (EPI == 3){ vv = vv / (rv[row] + 1e-8f); }
                else if (EPI == 4){ vv += bv + resid[(long)row * ldc + col]; }
                else if (EPI == 5 || EPI == 6){ vv = expf(vv - rv[row]) * scale; }
                else if (EPI == 8){ }
                else              { vv += bv; }
                if (EPI == 2 || EPI == 4 || EPI == 5 || EPI == 8) Cf[(long)row * ldc + col] = vv;
                else                                               Cb[(long)row * ldc + col] = f2b(vv);
            }
        }
    }
}

// tiled transpose: in f32 [R][C] -> out bf16 [C][R]; grid (C/64, R/64), 256 thr
__global__ __launch_bounds__(256)
void tr_kernel(const float* __restrict__ in, u16* __restrict__ out, long R, int C)
{
    __shared__ float t[64][65];
    const long cb = (long)blockIdx.x * 64, rb = (long)blockIdx.y * 64;
    const int tl = threadIdx.x & 63, tw = threadIdx.x >> 6;
    #pragma unroll
    for (int i = 0; i < 16; i++){
        const int r = tw + i * 4;
        t[r][tl] = in[(rb + r) * C + cb + tl];
    }
    __syncthreads();
    #pragma unroll
    for (int i = 0; i < 16; i++){
        const int c = tw + i * 4;
        out[(cb + c) * R + rb + tl] = f2b(t[tl][c]);
    }
}

// kptvb[b][i] = bf16( sum_{kc<7} kptv_all[b*7+kc][i] )
__global__ __launch_bounds__(256)
void kred_kernel(const float* __restrict__ in, u16* __restrict__ out, long n)
{
    long idx = (long)blockIdx.x * 256 + threadIdx.x;
    if (idx >= n) return;
    const long b = idx / 73728, r = idx - b * 73728;
    const float* s = in + b * 7 * 73728L + r;
    float acc = 0.f;
    #pragma unroll
    for (int kc = 0; kc < 7; kc++) acc += s[kc * 73728L];
    out[idx] = f2b(acc);
}

// LayerNorm over D=384 (f32 in); optional f32 and bf16 outputs.
__global__ __launch_bounds__(256)
void ln_kernel(const float* __restrict__ x, float* __restrict__ of, u16* __restrict__ ob,
               const float* __restrict__ g, const float* __restrict__ bta)
{
    const int lane = threadIdx.x & 63;
    const long r = (long)blockIdx.x * 4 + (threadIdx.x >> 6);
    const float* xr = x + r * 384;
    float v[6]; float s = 0.f;
    #pragma unroll
    for (int i = 0; i < 6; i++){ v[i] = xr[lane + i*64]; s += v[i]; }
    #pragma unroll
    for (int off = 32; off; off >>= 1) s += __shfl_xor(s, off);
    const float mu = s * (1.0f/384.0f);
    float q = 0.f;
    #pragma unroll
    for (int i = 0; i < 6; i++){ float d = v[i] - mu; q += d*d; }
    #pragma unroll
    for (int off = 32; off; off >>= 1) q += __shfl_xor(q, off);
    const float inv = rsqrtf(q * (1.0f/384.0f) + 1e-5f);
    #pragma unroll
    for (int i = 0; i < 6; i++){
        const int c = lane + i*64;
        const float val = (v[i] - mu) * inv * g[c] + bta[c];
        if (of) of[r * 384 + c] = val;
        if (ob) ob[r * 384 + c] = f2b(val);
    }
}

// xd[r] = 0.5*||x_row||^2 over 384 bf16 cols
__global__ __launch_bounds__(256)
void xd_b_kernel(const u16* __restrict__ x, float* __restrict__ xd)
{
    const int lane = threadIdx.x & 63;
    const long r = (long)blockIdx.x * 4 + (threadIdx.x >> 6);
    const u16* xr = x + r * 384;
    float s = 0.f;
    #pragma unroll
    for (int i = 0; i < 6; i++){ float a = b2f(xr[lane + i*64]); s += a*a; }
    #pragma unroll
    for (int off = 32; off; off >>= 1) s += __shfl_xor(s, off);
    if (lane == 0) xd[r] = 0.5f * s;
}

// Dn[r] = dot(qp_bf16[r,:192], kpsum[r/T,:192])
__global__ __launch_bounds__(256)
void dn_kernel(const u16* __restrict__ qp, const float* __restrict__ kpsum,
               float* __restrict__ Dn, int T)
{
    const int lane = threadIdx.x & 63;
    const long r = (long)blockIdx.x * 4 + (threadIdx.x >> 6);
    const int b = (int)(r / T);
    const u16* qr = qp + r * 192;
    const float* ks = kpsum + (long)b * 192;
    float s = 0.f;
    #pragma unroll
    for (int i = 0; i < 3; i++){ const int m = lane + i*64; s += b2f(qr[m]) * ks[m]; }
    #pragma unroll
    for (int off = 32; off; off >>= 1) s += __shfl_xor(s, off);
    if (lane == 0) Dn[r] = s;
}

__global__ __launch_bounds__(192)
void kpsum_kernel(const float* __restrict__ kp, float* __restrict__ kpsum)
{
    const int b = blockIdx.x, ch = blockIdx.y, m = threadIdx.x;
    const float* base = kp + ((long)b * 3136 + (long)ch * 448) * 192 + m;
    float s = 0.f;
    for (int t = 0; t < 448; t++) s += base[(long)t * 192];
    atomicAdd(&kpsum[b * 192 + m], s);
}

__global__ __launch_bounds__(256)
void zero_kernel(float* __restrict__ p, long n)
{
    long i = (long)blockIdx.x * 256 + threadIdx.x;
    long stride = (long)gridDim.x * 256;
    for (; i < n; i += stride) p[i] = 0.f;
}

// concat(in1,in2) row-major -> bf16 [Mc][768]
__global__ __launch_bounds__(256)
void ca_kernel(const float* __restrict__ i1, const float* __restrict__ i2,
               u16* __restrict__ a0, long nquad)
{
    long idx = (long)blockIdx.x * 256 + threadIdx.x;
    if (idx >= nquad) return;
    const long r = idx / 192;
    const int  c0 = (int)(idx % 192) * 4;
    const float* src = (c0 < 384) ? &i1[r * 384 + c0] : &i2[r * 384 + (c0 - 384)];
    float4 v = *(const float4*)src;
    u32 w0 = (u32)f2b(v.x) | ((u32)f2b(v.y) << 16);
    u32 w1 = (u32)f2b(v.z) | ((u32)f2b(v.w) << 16);
    *(uint2*)&a0[r * 768 + c0] = make_uint2(w0, w1);
}

// wt[n*K + k] = bf16(w[k*N + n])
__global__ __launch_bounds__(256)
void wt_kernel(const float* __restrict__ w, u16* __restrict__ wt, int K, int N, long total)
{
    long idx = (long)blockIdx.x * 256 + threadIdx.x;
    if (idx >= total) return;
    const long n = idx / K, k = idx - n * K;
    wt[idx] = f2b(w[k * N + n]);
}

// flat f32 -> bf16
__global__ __launch_bounds__(256)
void cvt_kernel(const float* __restrict__ s, u16* __restrict__ d, long n4)
{
    long idx = (long)blockIdx.x * 256 + threadIdx.x;
    if (idx >= n4) return;
    float4 v = *(const float4*)&s[idx * 4];
    u32 w0 = (u32)f2b(v.x) | ((u32)f2b(v.y) << 16);
    u32 w1 = (u32)f2b(v.z) | ((u32)f2b(v.w) << 16);
    *(uint2*)&d[idx * 4] = make_uint2(w0, w1);
}

extern "C" void kernel_launch(void* const* d_in, const int* in_sizes, int n_in,
                              void* d_out, int out_size, void* d_ws, size_t ws_size,
                              hipStream_t stream)
{
    const long T = 3136;
    const float prm_scale = 0.07216878364870322f;  // 1/sqrt(192)

    const float* in1    = (const float*)d_in[0];
    const float* in2    = (const float*)d_in[1];
    const float* W1     = (const float*)d_in[2];
    const float* b1     = (const float*)d_in[3];
    const float* W2     = (const float*)d_in[4];
    const float* b2     = (const float*)d_in[5];
    const float* kqv_w  = (const float*)d_in[6];
    const float* kqv_b  = (const float*)d_in[7];
    const float* proj_w = (const float*)d_in[8];
    const float* proj_b = (const float*)d_in[9];
    const float* ln1_g  = (const float*)d_in[10];
    const float* ln1_b  = (const float*)d_in[11];
    const float* ln2_g  = (const float*)d_in[12];
    const float* ln2_b  = (const float*)d_in[13];
    const float* mlp_w1 = (const float*)d_in[14];
    const float* mlp_b1 = (const float*)d_in[15];
    const float* mlp_w2 = (const float*)d_in[16];
    const float* mlp_b2 = (const float*)d_in[17];
    const float* w_prm  = (const float*)d_in[18];
    float* out = (float*)d_out;

    // ---- workspace layout ----
    char* p = (char*)d_ws;
    auto alloc = [&](long bytes)->char*{ char* r = p; p += (bytes + 255) & ~255L; return r; };

    // chunk-invariant bf16 weights
    u16* w1t   = (u16*)alloc(294912L * 2);   // [384][768]
    u16* w2t   = (u16*)alloc(147456L * 2);   // [384][384]
    u16* kqvt  = (u16*)alloc(442368L * 2);   // [1152][384]
    u16* prjt  = (u16*)alloc(147456L * 2);
    u16* m1t   = (u16*)alloc(147456L * 2);
    u16* m2t   = (u16*)alloc(147456L * 2);
    u16* wprmb = (u16*)alloc(256L * 384 * 2); // [256 pad][384], rows 192+ zeroed
    char* chunkBase = p;

    // per-batch ws bytes (see allocs below)
    const long perBatch = 2752L * T * 2 + 962L * T * 4
                        + (192L + 7L * 73728L) * 4 + 73728L * 2;
    const long fixed = (long)(chunkBase - (char*)d_ws) + (1L << 20);
    int nb = 2;
    for (int cand = 16; cand >= 2; cand >>= 1){
        if (fixed + (long)cand * perBatch + 128L * 1024 <= (long)ws_size){ nb = cand; break; }
    }

    const dim3 blk(256);

    // weight transpose/convert (idempotent per call)
    wt_kernel<<<dim3((294912 + 255) / 256), blk, 0, stream>>>(W1, w1t, 768, 384, 294912);
    wt_kernel<<<dim3((147456 + 255) / 256), blk, 0, stream>>>(W2, w2t, 384, 384, 147456);
    wt_kernel<<<dim3((442368 + 255) / 256), blk, 0, stream>>>(kqv_w, kqvt, 384, 1152, 442368);
    wt_kernel<<<dim3((147456 + 255) / 256), blk, 0, stream>>>(proj_w, prjt, 384, 384, 147456);
    wt_kernel<<<dim3((147456 + 255) / 256), blk, 0, stream>>>(mlp_w1, m1t, 384, 384, 147456);
    wt_kernel<<<dim3((147456 + 255) / 256), blk, 0, stream>>>(mlp_w2, m2t, 384, 384, 147456);
    zero_kernel<<<dim3(64), blk, 0, stream>>>((float*)wprmb, 256L * 384 / 2);
    cvt_kernel<<<dim3((18432 + 255) / 256), blk, 0, stream>>>(w_prm, wprmb, 18432);

    for (int b0 = 0; b0 < 16; b0 += nb){
        const long Mc = (long)nb * T;
        const int  gy128 = (int)(Mc / 128);
        const float* i1 = in1 + (long)b0 * T * 384;
        const float* i2 = in2 + (long)b0 * T * 384;
        float* outc = out + (long)b0 * T * 384;

        p = chunkBase;
        u16*  a0    = (u16*)alloc(Mc * 768 * 2);   // concat bf16 ; later mlp hidden
        u16*  h1b   = (u16*)alloc(Mc * 384 * 2);   // h1 bf16 ; later t_att bf16
        u16*  xnb   = (u16*)alloc(Mc * 384 * 2);   // xn bf16 ; later z bf16
        u16*  qpb   = (u16*)alloc(Mc * 192 * 2);   // qp bf16 (followed by allocs: OOB-read pad)
        u16*  kqb   = (u16*)alloc(Mc * 384 * 2);   // k bf16, then q bf16
        u16*  vT    = (u16*)alloc(384L * Mc * 2);  // v transposed bf16 [384][Mc]
        u16*  kpT   = (u16*)alloc(256L * Mc * 2);  // kp transposed bf16 [256 pad][Mc]
        float* xf   = (float*)alloc(Mc * 384 * 4); // x f32
        float* vf   = (float*)alloc(Mc * 384 * 4); // v f32
        float* kp   = (float*)alloc(Mc * 192 * 4); // kp f32
        float* xdv  = (float*)alloc(Mc * 4);
        float* Dn   = (float*)alloc(Mc * 4);
        float* kpsum= (float*)alloc((long)nb * 192 * 4);
        float* kptvA= (float*)alloc((long)nb * 7 * 73728 * 4);  // split-K slices
        u16*  kptvb = (u16*)alloc((long)nb * 73728 * 2);
        (void)alloc(128L * 1024);                   // tail pad

        // 0) a0 = bf16(concat)
        {
            long nq = Mc * 192;
            ca_kernel<<<dim3((unsigned)((nq + 255) / 256)), blk, 0, stream>>>(i1, i2, a0, nq);
        }
        // 1) h1 = GELU(a0 @ W1t^T + b1)  [bf16]
        gemm_bf16<1,0,0><<<dim3(3, gy128, 1), blk, 0, stream>>>(
            a0, 768, w1t, 768, h1b, 384, b1, nullptr, nullptr,
            (int)Mc, 384, 768, 1, 0,0,0,0, 0.f);
        // 2) x = h1 @ W2t^T + b2  [f32]
        gemm_bf16<2,0,0><<<dim3(3, gy128, 1), blk, 0, stream>>>(
            h1b, 384, w2t, 384, xf, 384, b2, nullptr, nullptr,
            (int)Mc, 384, 384, 1, 0,0,0,0, 0.f);
        // 3) LN1 -> xn bf16
        ln_kernel<<<dim3((unsigned)(Mc / 4)), blk, 0, stream>>>(xf, nullptr, xnb, ln1_g, ln1_b);
        // 4) k = xn @ kqvt[0:384] + b  [bf16]
        gemm_bf16<0,0,0><<<dim3(3, gy128, 1), blk, 0, stream>>>(
            xnb, 384, kqvt, 384, kqb, 384, kqv_b, nullptr, nullptr,
            (int)Mc, 384, 384, 1, 0,0,0,0, 0.f);
        xd_b_kernel<<<dim3((unsigned)(Mc / 4)), blk, 0, stream>>>(kqb, xdv);
        // 5) kp = exp(k @ wprm^T - xd)*scale  [f32, N=192 col-guarded]
        gemm_bf16<5,0,1><<<dim3(2, gy128, 1), blk, 0, stream>>>(
            kqb, 384, wprmb, 384, kp, 192, nullptr, xdv, nullptr,
            (int)Mc, 192, 384, 1, 0,0,0,0, prm_scale);
        // 6) kpsum
        zero_kernel<<<dim3(2), blk, 0, stream>>>(kpsum, (long)nb * 192);
        kpsum_kernel<<<dim3(nb, 7, 1), dim3(192), 0, stream>>>(kp, kpsum);
        // 7) q (overwrites kqb; kp GEMM already consumed k)
        gemm_bf16<0,0,0><<<dim3(3, gy128, 1), blk, 0, stream>>>(
            xnb, 384, kqvt + 384L * 384, 384, kqb, 384, kqv_b + 384, nullptr, nullptr,
            (int)Mc, 384, 384, 1, 0,0,0,0, 0.f);
        xd_b_kernel<<<dim3((unsigned)(Mc / 4)), blk, 0, stream>>>(kqb, xdv);
        gemm_bf16<6,0,1><<<dim3(2, gy128, 1), blk, 0, stream>>>(
            kqb, 384, wprmb, 384, qpb, 192, nullptr, xdv, nullptr,
            (int)Mc, 192, 384, 1, 0,0,0,0, prm_scale);
        // 8) v = xn @ kqvt[768:] + b  [f32]
        gemm_bf16<2,0,0><<<dim3(3, gy128, 1), blk, 0, stream>>>(
            xnb, 384, kqvt + 768L * 384, 384, vf, 384, kqv_b + 768, nullptr, nullptr,
            (int)Mc, 384, 384, 1, 0,0,0,0, 0.f);
        // 9) transposes: vf -> vT [384][Mc], kp -> kpT [192(256)][Mc]
        tr_kernel<<<dim3(6, (unsigned)(Mc / 64)), blk, 0, stream>>>(vf, vT, Mc, 384);
        tr_kernel<<<dim3(3, (unsigned)(Mc / 64)), blk, 0, stream>>>(kp, kpT, Mc, 192);
        // 10) kptv MFMA: [384][192] = vT(slice b) @ kpT(slice b)^T, split-K=7 slices
        gemm_bf16<8,0,1><<<dim3(2, 3, nb * 7), blk, 0, stream>>>(
            vT, (int)Mc, kpT, (int)Mc, kptvA, 192, nullptr, nullptr, nullptr,
            384, 192, 3136, 7, 3136, 3136, 73728, 0, 0.f);
        kred_kernel<<<dim3((unsigned)((long)nb * 73728 / 256)), blk, 0, stream>>>(
            kptvA, kptvb, (long)nb * 73728);
        // 11) Dn
        dn_kernel<<<dim3((unsigned)(Mc / 4)), blk, 0, stream>>>(qpb, kpsum, Dn, (int)T);
        // 12) t_att = (qp @ kptv^T) / (Dn+1e-8)  [bf16, per-batch, row-guarded]
        gemm_bf16<3,1,0><<<dim3(3, 25, nb), blk, 0, stream>>>(
            qpb, 192, kptvb, 192, h1b, 384, nullptr, Dn, nullptr,
            (int)T, 384, 192, 1, T*192, 73728, T*384, T, 0.f);
        // 13) y = t_att @ proj + proj_b + v  -> outc (f32)
        gemm_bf16<4,0,0><<<dim3(3, gy128, 1), blk, 0, stream>>>(
            h1b, 384, prjt, 384, outc, 384, proj_b, nullptr, vf,
            (int)Mc, 384, 384, 1, 0,0,0,0, 0.f);
        // 14) LN2 -> z bf16
        ln_kernel<<<dim3((unsigned)(Mc / 4)), blk, 0, stream>>>(outc, nullptr, xnb, ln2_g, ln2_b);
        // 15) h = GELU(z @ mlp1 + b)  [bf16] -> a0 region
        gemm_bf16<1,0,0><<<dim3(3, gy128, 1), blk, 0, stream>>>(
            xnb, 384, m1t, 384, a0, 384, mlp_b1, nullptr, nullptr,
            (int)Mc, 384, 384, 1, 0,0,0,0, 0.f);
        // 16) out = h @ mlp2 + b + y  (in-place residual on outc)
        gemm_bf16<4,0,0><<<dim3(3, gy128, 1), blk, 0, stream>>>(
            a0, 384, m2t, 384, outc, 384, mlp_b2, nullptr, outc,
            (int)Mc, 384, 384, 1, 0,0,0,0, 0.f);
    }
}